// Round 3
// baseline (4661.605 us; speedup 1.0000x reference)
//
#include <hip/hip_runtime.h>

// SDEBlock3D: ONE persistent kernel (plain launch, software global barrier)
// runs all 20 Euler-Maruyama steps: conv1 -> gbar -> conv2 -> gbar per step.
// 256 blocks x 512 thr = exactly 1 block/CU (robust co-residency; VGPR<=256
// via launch_bounds, LDS 16KB). Barrier = device-scope atomics + threadfence
// (same fence sequence grid.sync() emits), graph-capture-safe.
//   y   fp32 [16][64^3] channel-major, master state in d_out.
//   ybp bf16 [66][66][66][16] channels-last padded (conv1 input), in d_ws.
//   hbp bf16 [66][66][66][64] channels-last padded (conv2 input), in d_ws.
// conv1 uses z-rotation accumulators (9 B-loads per 27 MFMAs); conv2 keeps
// the verified R1 rotation form. Addressing identical to R1 (verified).

#define S    64
#define SS   4096
#define SSS  262144
#define DT_F 0.05f
#define SIG_SDT 0.022360679774997897f  // 0.1*sqrt(0.05)
#define PD   66                        // padded side (halo of 1 each side)
#define NBLK 256

typedef __bf16 bf16x8 __attribute__((ext_vector_type(8)));
typedef float  f32x4  __attribute__((ext_vector_type(4)));
typedef float  f32x16 __attribute__((ext_vector_type(16)));

union B8U { uint4 u; bf16x8 b; };
__device__ inline bf16x8 as_bf16x8(uint4 u) { B8U x; x.u = u; return x.b; }

__device__ inline unsigned short bf16_bits(float f) {
    union { float f; unsigned u; } c; c.f = f;
    unsigned r = c.u + 0x7fffu + ((c.u >> 16) & 1u);   // RNE
    return (unsigned short)(r >> 16);
}

// tanh = 1 - 2/(e^{2v}+1): e=inf -> 1, e=0 -> -1; no clamp needed, no NaN.
__device__ inline float tanh_fast(float v) {
    float e = __expf(2.f * v);
    return 1.f - 2.f * __builtin_amdgcn_rcpf(e + 1.f);
}

// ---------------------------------------------------------------------------
__global__ void zero_ws(uint4* __restrict__ p, unsigned n)
{
    const uint4 z = {0u, 0u, 0u, 0u};
    for (unsigned i = blockIdx.x * 256u + threadIdx.x; i < n; i += gridDim.x * 256u)
        p[i] = z;
}

// w1t: frag(tap, mtile): lane l elem j -> A[m=mt*32+(l&31)][k=(l>>5)*8+j]
// w2t: frag(tap, kc)   : lane l elem j -> A[m=l&15][k=(l>>4)*8+j], ic=kc*32+k
// Also zeroes the global-barrier counters (re-run every replay).
__global__ void prep_weights(const float* __restrict__ w1, const float* __restrict__ w2,
                             unsigned short* __restrict__ w1t, unsigned short* __restrict__ w2t,
                             unsigned* __restrict__ bar)
{
    const int t = blockIdx.x * 256 + threadIdx.x;
    if (blockIdx.x == 0 && threadIdx.x < 64) bar[threadIdx.x] = 0u;
    if (t >= 27 * 2 * 64 * 8) return;
    const int j = t & 7, l = (t >> 3) & 63, half = (t >> 9) & 1, tap = t >> 10;
    {
        const int oc = half * 32 + (l & 31), ic = (l >> 5) * 8 + j;
        w1t[t] = bf16_bits(w1[(oc * 16 + ic) * 27 + tap]);
    }
    {
        const int oc = l & 15, ic = half * 32 + (l >> 4) * 8 + j;
        w2t[t] = bf16_bits(w2[(oc * 64 + ic) * 27 + tap]);
    }
}

// x fp32 [16][S^3] -> ybp bf16 padded [z+1][y+1][x+1][16]
__global__ void pack_x(const float* __restrict__ x, char* __restrict__ ybp)
{
    const int p = blockIdx.x * 256 + threadIdx.x;
    const int z = p >> 12, yy = (p >> 6) & 63, xx = p & 63;
    union { unsigned short s[16]; uint4 v[2]; } pk;
    #pragma unroll
    for (int c = 0; c < 16; ++c) pk.s[c] = bf16_bits(x[c * SSS + p]);
    char* dst = ybp + (((size_t)(z + 1) * PD + (yy + 1)) * PD + (xx + 1)) * 32;
    *(uint4*)dst        = pk.v[0];
    *(uint4*)(dst + 16) = pk.v[1];
}

// ---------------------------------------------------------------------------
// Software grid barrier: arrive (acq_rel add) + spin on generation (acquire).
// __threadfence() = agent-scope fence -> L2 writeback / L1+L2 invalidate, so
// cross-XCD data written before the barrier is visible after it. Leader-only
// fence covers the CU (all waves of the block share that CU's L1).
// ---------------------------------------------------------------------------
__device__ inline void gbar(unsigned* cnt, unsigned* gen)
{
    __syncthreads();
    if (threadIdx.x == 0) {
        __threadfence();
        unsigned g0 = __hip_atomic_load(gen, __ATOMIC_RELAXED, __HIP_MEMORY_SCOPE_AGENT);
        unsigned a  = __hip_atomic_fetch_add(cnt, 1u, __ATOMIC_ACQ_REL, __HIP_MEMORY_SCOPE_AGENT);
        if (a == NBLK - 1u) {
            __hip_atomic_store(cnt, 0u, __ATOMIC_RELAXED, __HIP_MEMORY_SCOPE_AGENT);
            __hip_atomic_fetch_add(gen, 1u, __ATOMIC_RELEASE, __HIP_MEMORY_SCOPE_AGENT);
        } else {
            unsigned gg;
            do {
                __builtin_amdgcn_s_sleep(8);
                gg = __hip_atomic_load(gen, __ATOMIC_ACQUIRE, __HIP_MEMORY_SCOPE_AGENT);
            } while (gg == g0);
        }
        __threadfence();
    }
    __syncthreads();
}

// ---------------------------------------------------------------------------
__global__ __launch_bounds__(512, 2)
void sde_mega(const uint4* __restrict__ w1t, const uint4* __restrict__ w2t,
              const float* __restrict__ b1, const float* __restrict__ b2,
              const float* __restrict__ x, float* __restrict__ yst,
              char* __restrict__ ybp, char* __restrict__ hbp,
              const float* __restrict__ noise, unsigned* bar)
{
    __shared__ f32x4 scratch[2][2][2][64];   // [zs][xh2][ping][lane]
    const int t = threadIdx.x, lane = t & 63, w = t >> 6;
    // XCD swizzle (256 = 8*32, bijective): each XCD one contiguous chunk.
    const int bs = ((int)blockIdx.x & 7) * 32 + ((int)blockIdx.x >> 3);
    const int yy = bs & 63, bz = bs >> 6;    // y row, z quarter (16 planes)

    const int n   = lane & 31, hh = lane >> 5;   // conv1 lane roles
    const int n16 = lane & 15, g  = lane >> 4;   // conv2 lane roles
    const int zs  = w >> 2;                      // z sub-chunk of 8 (both)
    const int mt  = (w >> 1) & 1, xg1 = w & 1;   // conv1 wave roles
    const int xh2 = (w >> 1) & 1, kc  = w & 1;   // conv2 wave roles
    const int z0  = bz * 16 + zs * 8;

    unsigned* cnt = bar;
    unsigned* gen = bar + 32;

    #pragma unroll 1
    for (int s = 0; s < 20; ++s) {
        // ---------------- conv1: ybp -> hbp (bias + tanh fused) ----------------
        {
            asm volatile("" ::: "memory");   // keep A/bias live-range per-step
            bf16x8 A[27];
            #pragma unroll
            for (int tap = 0; tap < 27; ++tap)
                A[tap] = as_bf16x8(w1t[(tap * 2 + mt) * 64 + lane]);
            float bias[16];
            #pragma unroll
            for (int q = 0; q < 4; ++q)
                #pragma unroll
                for (int j = 0; j < 4; ++j)
                    bias[q * 4 + j] = b1[mt * 32 + q * 8 + hh * 4 + j];

            const char* ybl = ybp + (xg1 * 32 + n) * 32 + hh * 16;
            char* hbl = hbp + ((size_t)(yy + 1) * PD + (xg1 * 32 + n + 1)) * 128
                            + (mt * 32 + hh * 4) * 2;

            f32x16 acc[3];
            #pragma unroll
            for (int r = 0; r < 3; ++r)
                #pragma unroll
                for (int q = 0; q < 16; ++q) acc[r][q] = 0.f;

            #pragma unroll
            for (int i = 0; i < 10; ++i) {
                const int zp = z0 - 1 + i;   // input plane (unpadded coords)
                const char* pb = ybl + ((size_t)(zp + 1) * PD + yy) * (PD * 32);
                #pragma unroll
                for (int dy = 0; dy < 3; ++dy)
                    #pragma unroll
                    for (int dx = 0; dx < 3; ++dx) {
                        bf16x8 B = as_bf16x8(*(const uint4*)(pb + (dy * PD + dx) * 32));
                        if (i < 8)                  // out z = zp+1, tap dz=0
                            acc[(i + 1) % 3] = __builtin_amdgcn_mfma_f32_32x32x16_bf16(
                                A[0 + dy * 3 + dx], B, acc[(i + 1) % 3], 0, 0, 0);
                        if (i >= 1 && i <= 8)       // out z = zp,   tap dz=1
                            acc[i % 3] = __builtin_amdgcn_mfma_f32_32x32x16_bf16(
                                A[9 + dy * 3 + dx], B, acc[i % 3], 0, 0, 0);
                        if (i >= 2)                 // out z = zp-1, tap dz=2
                            acc[(i + 2) % 3] = __builtin_amdgcn_mfma_f32_32x32x16_bf16(
                                A[18 + dy * 3 + dx], B, acc[(i + 2) % 3], 0, 0, 0);
                    }
                if (i >= 2) {                       // output plane z0+i-2 done
                    const int z = z0 + i - 2;
                    char* hp = hbl + (size_t)(z + 1) * (PD * PD * 128);
                    f32x16 a = acc[(i + 2) % 3];
                    // D 32x32: col = lane&31 (=px), row = (reg&3)+8*(reg>>2)+4*hh
                    #pragma unroll
                    for (int q = 0; q < 4; ++q) {
                        union { unsigned short sh[4]; uint2 v; } pk;
                        #pragma unroll
                        for (int j = 0; j < 4; ++j)
                            pk.sh[j] = bf16_bits(tanh_fast(a[q * 4 + j] + bias[q * 4 + j]));
                        *(uint2*)(hp + q * 16) = pk.v;
                    }
                    #pragma unroll
                    for (int q = 0; q < 16; ++q) acc[(i + 2) % 3][q] = 0.f;
                }
            }
        }
        gbar(cnt, gen);
        // ---------------- conv2: hbp -> Euler update (y, ybp) ----------------
        {
            asm volatile("" ::: "memory");
            bf16x8 A[27];
            #pragma unroll
            for (int tap = 0; tap < 27; ++tap)
                A[tap] = as_bf16x8(w2t[(tap * 2 + kc) * 64 + lane]);
            float b2v[4];
            #pragma unroll
            for (int j = 0; j < 4; ++j) b2v[j] = b2[g * 4 + j];

            const float* ysrc = (s == 0) ? x : yst;
            const float* nz = noise + (size_t)s * (16 * SSS);

            #pragma unroll 1
            for (int xt = 0; xt < 2; ++xt) {
                const int x0 = xh2 * 32 + xt * 16;
                const char* hbl = hbp + (x0 + n16) * 128 + kc * 64 + g * 16;

                f32x4 acc[3];
                #pragma unroll
                for (int r = 0; r < 3; ++r)
                    #pragma unroll
                    for (int q = 0; q < 4; ++q) acc[r][q] = 0.f;

                #pragma unroll
                for (int i = 0; i < 10; ++i) {
                    const int zp = z0 - 1 + i;
                    const char* pb = hbl + ((size_t)(zp + 1) * PD + yy) * (PD * 128);
                    #pragma unroll
                    for (int dy = 0; dy < 3; ++dy)
                        #pragma unroll
                        for (int dx = 0; dx < 3; ++dx) {
                            bf16x8 B = as_bf16x8(*(const uint4*)(pb + (dy * PD + dx) * 128));
                            if (i < 8)
                                acc[(i + 1) % 3] = __builtin_amdgcn_mfma_f32_16x16x32_bf16(
                                    A[0 + dy * 3 + dx], B, acc[(i + 1) % 3], 0, 0, 0);
                            if (i >= 1 && i <= 8)
                                acc[i % 3] = __builtin_amdgcn_mfma_f32_16x16x32_bf16(
                                    A[9 + dy * 3 + dx], B, acc[i % 3], 0, 0, 0);
                            if (i >= 2)
                                acc[(i + 2) % 3] = __builtin_amdgcn_mfma_f32_16x16x32_bf16(
                                    A[18 + dy * 3 + dx], B, acc[(i + 2) % 3], 0, 0, 0);
                        }
                    if (i >= 2) {
                        const int z = z0 + i - 2;
                        f32x4 a = acc[(i + 2) % 3];
                        #pragma unroll
                        for (int q = 0; q < 4; ++q) acc[(i + 2) % 3][q] = 0.f;
                        if (kc == 1) scratch[zs][xh2][i & 1][lane] = a;
                        __syncthreads();
                        if (kc == 0) {
                            f32x4 o = scratch[zs][xh2][i & 1][lane];
                            // D 16x16: col = lane&15 (=px), row = g*4 + reg (=oc)
                            const size_t p = (size_t)z * SS + yy * S + (x0 + n16);
                            union { unsigned short sh[4]; uint2 v; } pk;
                            #pragma unroll
                            for (int j = 0; j < 4; ++j) {
                                const size_t idx = (size_t)(g * 4 + j) * SSS + p;
                                const float f = a[j] + o[j] + b2v[j];
                                const float yv = ysrc[idx] + f * DT_F + SIG_SDT * nz[idx];
                                yst[idx] = yv;
                                pk.sh[j] = bf16_bits(yv);
                            }
                            char* yb = ybp + (((size_t)(z + 1) * PD + (yy + 1)) * PD
                                              + (x0 + n16 + 1)) * 32 + g * 8;
                            *(uint2*)yb = pk.v;
                        }
                    }
                }
            }
        }
        gbar(cnt, gen);
    }
}

// ---------------------------------------------------------------------------
extern "C" void kernel_launch(void* const* d_in, const int* in_sizes, int n_in,
                              void* d_out, int out_size, void* d_ws, size_t ws_size,
                              hipStream_t stream)
{
    (void)in_sizes; (void)n_in; (void)out_size; (void)ws_size;
    const float* x     = (const float*)d_in[0];
    // d_in[1] = integration_time (unused; dt=0.05, 20 steps fixed)
    const float* w1    = (const float*)d_in[2];
    const float* b1    = (const float*)d_in[3];
    const float* w2    = (const float*)d_in[4];
    const float* b2    = (const float*)d_in[5];
    const float* noise = (const float*)d_in[6];

    char* ws = (char*)d_ws;
    unsigned short* w1t = (unsigned short*)ws;            // 55296 B
    unsigned short* w2t = (unsigned short*)(ws + 55296);  // 55296 B
    unsigned* bar = (unsigned*)(ws + 110592);             // 256 B barrier state
    char* ybp = ws + 131072;                              // 66^3*32  = 9,199,872 B
    char* hbp = ws + 131072 + 9199872;                    // 66^3*128 = 36,799,488 B
    float* y  = (float*)d_out;

    zero_ws<<<2048, 256, 0, stream>>>((uint4*)ybp, (9199872u + 36799488u) / 16u);
    prep_weights<<<108, 256, 0, stream>>>(w1, w2, w1t, w2t, bar);
    pack_x<<<1024, 256, 0, stream>>>(x, ybp);

    sde_mega<<<dim3(NBLK), dim3(512), 0, stream>>>(
        (const uint4*)w1t, (const uint4*)w2t, b1, b2, x, y, ybp, hbp, noise, bar);
}